// Round 9
// baseline (198.630 us; speedup 1.0000x reference)
//
#include <hip/hip_runtime.h>
#include <math.h>

#define HDIM 512
#define NH   32
#define LTOT 8192
#define TPB  256
#define BANDL 512   // l per wave-band; 16 bands per h
#define REPS 8      // DIAGNOSTIC: in-kernel repeat to surface s4_kernel in rocprof

typedef float v2f __attribute__((ext_vector_type(2)));

// Round 9 DIAGNOSTIC: identical math to round 8, but the accumulate+store body
// runs REPS=8 times inside the single launch (opaque register barrier on l0f
// prevents CSE across reps; stores re-write identical values -> output
// unchanged). Purpose: s4_kernel has NEVER appeared in the top-5 counter
// table (always < 40us fills). With ~8x exec it becomes the top dispatch and
// we finally read ITS VALUBusy / Occupancy / WRITE_SIZE / LDS conflicts to
// attribute the ~9us gap between the issue model (~3us) and measured (~12us).
__global__ __launch_bounds__(TPB, 8) void s4_kernel(
    const float* __restrict__ log_dt,
    const float* __restrict__ log_A_real,
    const float* __restrict__ A_imag,
    const float* __restrict__ Bmat,
    const float* __restrict__ Cmat,
    float* __restrict__ out)
{
    __shared__ float4 p0[NH]; // key=re*log2e, im/(2pi), w256r, w256i
    __shared__ float4 p1[NH]; // E0r, E1r, E0i, E1i   (Ej = 2*Ceff*w^j)
    __shared__ float4 p2[NH]; // E2r, E3r, E2i, E3i

    const int bid  = blockIdx.x;
    const int h    = bid & (HDIM - 1);   // q-major ordering: bid = q*HDIM + h
    const int q    = bid >> 9;
    const int tid  = threadIdx.x;

    if (tid < NH) {
        const int n   = tid;
        const int idx = h * NH + n;
        const float dt = expf(log_dt[h]);
        const float Ar = -expf(log_A_real[idx]);   // A = -exp(lar) - i*A_imag
        const float Ai = -A_imag[idx];
        const float re = Ar * dt;                  // dtA (re < 0)
        const float im = Ai * dt;
        float sw, cw;
        sincosf(im, &sw, &cw);                     // precise: small arg
        const float er = expf(re);
        const float wr = er * cw;                  // w = exp(dtA)
        const float wi = er * sw;
        // (w - 1) / A
        const float inv = 1.0f / (Ar * Ar + Ai * Ai);
        const float nr = wr - 1.0f, ni = wi;
        const float qr = (nr * Ar + ni * Ai) * inv;
        const float qi = (ni * Ar - nr * Ai) * inv;
        // E0 = 2 * Bc * Cc * (w-1)/A
        const float Br = Bmat[2 * idx], Bi = Bmat[2 * idx + 1];
        const float Cr = Cmat[2 * idx], Ci = Cmat[2 * idx + 1];
        const float bcr = Br * Cr - Bi * Ci;
        const float bci = Br * Ci + Bi * Cr;
        const float e0r = 2.0f * (bcr * qr - bci * qi);
        const float e0i = 2.0f * (bcr * qi + bci * qr);
        // Ej = E0 * w^j
        const float e1r = e0r * wr - e0i * wi, e1i = e0r * wi + e0i * wr;
        const float e2r = e1r * wr - e1i * wi, e2i = e1r * wi + e1i * wr;
        const float e3r = e2r * wr - e2i * wi, e3i = e2r * wi + e2i * wr;
        // w^256 = exp(256*dtA), computed directly (exact, no accumulation)
        float s256, c256;
        sincosf(256.0f * im, &s256, &c256);
        const float er256 = expf(256.0f * re);     // underflow -> 0, fine
        const float w256r = er256 * c256;
        const float w256i = er256 * s256;

        // Rank-sort poles by decay rate, slowest (key closest to 0) first.
        const float key = re * 1.44269504089f;
        int rank = 0;
#pragma unroll
        for (int m = 0; m < NH; ++m) {
            const float km = __shfl(key, m, 64);
            rank += (km > key || (km == key && m < n)) ? 1 : 0;
        }
        p0[rank] = make_float4(key, im * 0.15915494309f, w256r, w256i);
        p1[rank] = make_float4(e0r, e1r, e0i, e1i);
        p2[rank] = make_float4(e2r, e3r, e2i, e3i);
    }
    __syncthreads();

    const int wave = tid >> 6;
    const int lane = tid & 63;
    const int band = wave * 4 + q;               // stride-4 decay sampling
    const int Lb   = band * BANDL;
    const int l0   = Lb + lane * 4;              // quad0; quad1 = l0 + 256
    float l0f = (float)l0;
    const float Lbf = (float)Lb;                 // wave-uniform min l

    float4* outq = (float4*)(out + (size_t)h * LTOT + Lb);

#pragma unroll 1
    for (int rep = 0; rep < REPS; ++rep) {
        // Opaque barrier: compiler must treat l0f as possibly-changed, so the
        // full per-rep computation stays live (no CSE across reps).
        asm volatile("" : "+v"(l0f));

        v2f acc2[4];
#pragma unroll
        for (int k = 0; k < 4; ++k) acc2[k] = v2f{0.0f, 0.0f};

#pragma unroll 1
        for (int n = 0; n < NH; ++n) {
            const float4 P0 = p0[n];
            // Sorted by decay: first dead pole at this wave's min l => all
            // later poles dead too.
            if (P0.x * Lbf < -17.3f) break;    // 2^-17.3 ~ 6e-6
            const float4 Q1 = p1[n];
            const float4 Q2 = p2[n];
            float ph = P0.y * l0f;             // phase in revolutions
            ph = __builtin_amdgcn_fractf(ph);
            const float s = __builtin_amdgcn_sinf(ph);   // sin(2*pi*ph)
            const float c = __builtin_amdgcn_cosf(ph);
            const float e = __builtin_amdgcn_exp2f(P0.x * l0f); // ->0 past cut
            const float kr = e * c;            // K(l0) = exp(dtA*l0)
            const float ki = e * s;
            // quad0: u_j = Re(Ej * K(l0))
            acc2[0] += v2f{Q1.x, Q1.y} * kr - v2f{Q1.z, Q1.w} * ki;
            acc2[1] += v2f{Q2.x, Q2.y} * kr - v2f{Q2.z, Q2.w} * ki;
            // quad1: K' = K * w^256
            const float k2r = kr * P0.z - ki * P0.w;
            const float k2i = kr * P0.w + ki * P0.z;
            acc2[2] += v2f{Q1.x, Q1.y} * k2r - v2f{Q1.z, Q1.w} * k2i;
            acc2[3] += v2f{Q2.x, Q2.y} * k2r - v2f{Q2.z, Q2.w} * k2i;
        }

        // Lane-contiguous float4 stores (1024B fully-covered per wave instr).
        outq[lane]      = make_float4(acc2[0].x, acc2[0].y,
                                      acc2[1].x, acc2[1].y);
        outq[64 + lane] = make_float4(acc2[2].x, acc2[2].y,
                                      acc2[3].x, acc2[3].y);
    }
}

extern "C" void kernel_launch(void* const* d_in, const int* in_sizes, int n_in,
                              void* d_out, int out_size, void* d_ws, size_t ws_size,
                              hipStream_t stream)
{
    (void)in_sizes; (void)n_in; (void)d_ws; (void)ws_size; (void)out_size;
    const float* log_dt     = (const float*)d_in[0];
    const float* log_A_real = (const float*)d_in[1];
    const float* A_imag     = (const float*)d_in[2];
    const float* Bmat       = (const float*)d_in[3];
    const float* Cmat       = (const float*)d_in[4];
    float* out = (float*)d_out;

    s4_kernel<<<dim3(HDIM * 4), dim3(TPB), 0, stream>>>(
        log_dt, log_A_real, A_imag, Bmat, Cmat, out);
}